// Round 3
// baseline (632.838 us; speedup 1.0000x reference)
//
#include <hip/hip_runtime.h>
#include <math.h>

// GraphSwinWindowContext: B=32, H=W=192, C=64, WS=6, SS=3, NH=NW=32. fp32 in/out.
//
// Output has only B*32*32*4 = 131072 distinct C-vectors (constant per
// (window, quadrant) 3x3 patch) -> per-pixel 64x64 linears collapse 9x.
//
// Round-6 changes vs round 5 (632us; round 4 was 622us):
//  * r5's smem_row64 asm blocked on lgkmcnt(0) inside the asm per row ->
//    serial scalar-load round trips the compiler couldn't hoist. Replaced
//    with PLAIN C++ uniform loads off a readfirstlane-uniform base: compiler
//    emits batched s_load_dwordx16 + relaxed waitcnt, hoists across rows,
//    and still uses the SGPR operand directly in v_fmac (no readlane, no
//    per-lane x VGPRs).
//  * k_outbc: 2-row interleave -> two independent fmac/butterfly/gelu chains
//    per wave; the 6-deep shfl_xor variance chain hides under the sibling
//    row's fmacs.
//  * k_prep folded into k_blocksum (block 2048) -> one fewer launch, prep
//    hidden under the memory-bound blocksum.
//  * Centered weights kept (k_prep): mean(y)==0 exactly -> LN needs only the
//    variance butterfly.
//
// Pipeline:
//  A) k_blocksum: 3x3-pixel block sums + weight centering    (reads 302MB)
//  B) k_token:    pooled(reg/shift) -> lin+LN+GELU -> tok    (65536 rows)
//  C) k_fuse:     tokreg+tokshift -> lin+LN+GELU -> h1       (131072 rows)
//  D) k_outbc:    h1 -> lin+LN+GELU -> broadcast 3x3 to out  (writes 302MB)
//
// ws layout:
//  [0, 33554432)        : S fp32 [B][64][64][C]   -- reused as h1 after k_token
//  [33554432, 50331648) : tok fp32 [2][B][32][32][C]
//  [67108864, +49.4KB)  : centered Wt',Wf',Wo' (4096 fl each) + bt',bf',bo'

#define HH 192
#define WW 192
#define CC 64

__device__ __forceinline__ float gelu_exact(float x) {
    return 0.5f * x * (1.0f + erff(x * 0.70710678118654752440f));
}
__device__ __forceinline__ float wsum64(float v) {
#pragma unroll
    for (int off = 32; off > 0; off >>= 1) v += __shfl_xor(v, off, 64);
    return v;
}
// Broadcast lane k's value to all lanes: v_readlane_b32 (VALU, no DS).
__device__ __forceinline__ float bcast(float v, int k) {
    return __int_as_float(__builtin_amdgcn_readlane(__float_as_int(v), k));
}
// LN with pre-centered weights: mean(y)==0, only variance needs a reduction.
__device__ __forceinline__ float ln_gelu_c(float y, float g, float b) {
    float s2 = y * y;
#pragma unroll
    for (int off = 32; off > 0; off >>= 1) s2 += __shfl_xor(s2, off, 64);
    float v = s2 * (1.0f / 64.0f);
    return gelu_exact(y * rsqrtf(v + 1e-5f) * g + b);
}
// Readlane matvec (k_token: input row lives per-lane in registers).
__device__ __forceinline__ float matvec64(float m, const float* Wc, float bias) {
    float y0 = bias, y1 = 0.f, y2 = 0.f, y3 = 0.f;
#pragma unroll
    for (int k = 0; k < 64; k += 4) {
        y0 += bcast(m, k)     * Wc[k];
        y1 += bcast(m, k + 1) * Wc[k + 1];
        y2 += bcast(m, k + 2) * Wc[k + 2];
        y3 += bcast(m, k + 3) * Wc[k + 3];
    }
    return (y0 + y1) + (y2 + y3);
}

// ------- Kernel A: 3x3 pixel-block channel sums + weight centering ----------
// blocks 0..2047: S[b][by][bx][c] = sum_{3x3} grid. block 2048: center W,b.
extern "C" __global__ __launch_bounds__(256)
void k_blocksum(const float* __restrict__ h, float* __restrict__ S,
                const float* __restrict__ W0, const float* __restrict__ b0,
                const float* __restrict__ W1, const float* __restrict__ b1,
                const float* __restrict__ W2, const float* __restrict__ b2,
                float* __restrict__ cw) {
    if (blockIdx.x == 2048) {                 // ---- prep path (3 waves) ----
        if (threadIdx.x >= 192) return;
        int lane = threadIdx.x & 63;
        int w = threadIdx.x >> 6;             // 0..2
        const float* W  = (w == 0) ? W0 : (w == 1) ? W1 : W2;
        const float* bs = (w == 0) ? b0 : (w == 1) ? b1 : b2;
        float* Wo = cw + w * 4096;
        float* bo = cw + 12288 + w * 64;
        for (int k = 0; k < 64; ++k) {
            float v = W[k * 64 + lane];
            Wo[k * 64 + lane] = v - wsum64(v) * (1.0f / 64.0f);
        }
        float bv = bs[lane];
        bo[lane] = bv - wsum64(bv) * (1.0f / 64.0f);
        return;
    }
    int bby = blockIdx.x;                     // b*64 + by
    int b = bby >> 6, by = bby & 63;
    for (int item = threadIdx.x; item < 512; item += 256) {
        int bx = item >> 3;
        int c0 = (item & 7) * 8;
        float acc[8] = {0.f, 0.f, 0.f, 0.f, 0.f, 0.f, 0.f, 0.f};
#pragma unroll
        for (int dy = 0; dy < 3; ++dy) {
#pragma unroll
            for (int dx = 0; dx < 3; ++dx) {
                int y = by * 3 + dy, x = bx * 3 + dx;
                const float4* p = reinterpret_cast<const float4*>(
                    h + (((size_t)b * HH + y) * WW + x) * CC + c0);
                float4 v0 = p[0], v1 = p[1];
                acc[0] += v0.x; acc[1] += v0.y; acc[2] += v0.z; acc[3] += v0.w;
                acc[4] += v1.x; acc[5] += v1.y; acc[6] += v1.z; acc[7] += v1.w;
            }
        }
        float4* o = reinterpret_cast<float4*>(S + (((size_t)bby) * 64 + bx) * CC + c0);
        o[0] = make_float4(acc[0], acc[1], acc[2], acc[3]);
        o[1] = make_float4(acc[4], acc[5], acc[6], acc[7]);
    }
}

// ---------------- Kernel B: token projection (reg + shifted) ----------------
// rows: mode(2) x b(32) x wy(32) x wx(32) = 65536; one wave computes 16 rows.
extern "C" __global__ __launch_bounds__(256)
void k_token(const float* __restrict__ S,
             const float* __restrict__ Wt, const float* __restrict__ bt,
             const float* __restrict__ gt, const float* __restrict__ bet,
             float* __restrict__ tok) {
    int lane = threadIdx.x & 63;
    int wg = blockIdx.x * 4 + (threadIdx.x >> 6);
    float Wc[64];
#pragma unroll
    for (int k = 0; k < 64; ++k) Wc[k] = Wt[k * 64 + lane];
    float bias = bt[lane], gg = gt[lane], bb = bet[lane];
    int row0 = wg * 16;
    for (int i = 0; i < 16; ++i) {
        int row = row0 + i;
        int mode = row >> 15;
        int r = row & 32767;
        int b = r >> 10, wy = (r >> 5) & 31, wx = r & 31;
        int r0, r1, c0, c1;
        if (mode == 0) { r0 = 2 * wy;     r1 = 2 * wy + 1;        c0 = 2 * wx;     c1 = 2 * wx + 1; }
        else           { r0 = 2 * wy + 1; r1 = (2 * wy + 2) & 63; c0 = 2 * wx + 1; c1 = (2 * wx + 2) & 63; }
        const float* Sb = S + (size_t)b * 64 * 64 * 64;
        float pooled = (Sb[(r0 * 64 + c0) * 64 + lane] + Sb[(r0 * 64 + c1) * 64 + lane] +
                        Sb[(r1 * 64 + c0) * 64 + lane] + Sb[(r1 * 64 + c1) * 64 + lane]) * (1.0f / 36.0f);
        float y = matvec64(pooled, Wc, bias);
        tok[(size_t)row * 64 + lane] = ln_gelu_c(y, gg, bb);
    }
}

// ------- Kernel C: fuse block (uniform s_load matvec, window-shared) --------
// rows: b(5)|wy(5)|wx(5)|q(2) = 131072; one wave = 4 windows x 4 quadrants.
extern "C" __global__ __launch_bounds__(256)
void k_fuse(const float* __restrict__ tok,
            const float* __restrict__ Wf, const float* __restrict__ bf_,
            const float* __restrict__ gf, const float* __restrict__ bef,
            float* __restrict__ h1) {
    int lane = threadIdx.x & 63;
    int wid = __builtin_amdgcn_readfirstlane(threadIdx.x >> 6);
    int wg = blockIdx.x * 4 + wid;
    float Wc[64];
#pragma unroll
    for (int k = 0; k < 64; ++k) Wc[k] = Wf[k * 64 + lane];
    float fb = bf_[lane], fg = gf[lane], fbe = bef[lane];
    int row0 = wg * 16;                       // q bits 0 -> wx0 % 4 == 0
    int b = row0 >> 12;
    int rem = row0 & 4095;
    int wy = rem >> 7, wx0 = (rem >> 2) & 31;
    const float* t0 = tok + (size_t)b * 65536;
    const float* t1 = tok + 2097152 + (size_t)b * 65536;
    for (int j = 0; j < 4; ++j) {
        int wx = wx0 + j;                     // <= 31, no wrap
        // shared term: bias + t0[wy][wx] @ W  (computed once for 4 quadrants).
        // r0p is wave-uniform -> compiler scalarizes to batched s_load and
        // feeds v_fmac's SGPR operand; no per-lane x registers.
        const float* r0p = t0 + (wy * 32 + wx) * 64;
        float s0 = fb, s1 = 0.f, s2 = 0.f, s3 = 0.f;
#pragma unroll
        for (int k = 0; k < 64; k += 4) {
            s0 = fmaf(r0p[k + 0], Wc[k + 0], s0);
            s1 = fmaf(r0p[k + 1], Wc[k + 1], s1);
            s2 = fmaf(r0p[k + 2], Wc[k + 2], s2);
            s3 = fmaf(r0p[k + 3], Wc[k + 3], s3);
        }
#pragma unroll
        for (int q = 0; q < 4; ++q) {
            int sy = (wy + 31 + (q >> 1)) & 31;
            int sx = (wx + 31 + (q & 1)) & 31;
            const float* r1p = t1 + (sy * 32 + sx) * 64;
            float y0 = s0, y1 = s1, y2 = s2, y3 = s3;
#pragma unroll
            for (int k = 0; k < 64; k += 4) {
                y0 = fmaf(r1p[k + 0], Wc[k + 0], y0);
                y1 = fmaf(r1p[k + 1], Wc[k + 1], y1);
                y2 = fmaf(r1p[k + 2], Wc[k + 2], y2);
                y3 = fmaf(r1p[k + 3], Wc[k + 3], y3);
            }
            float y = (y0 + y1) + (y2 + y3);
            h1[(size_t)(row0 + j * 4 + q) * 64 + lane] = ln_gelu_c(y, fg, fbe);
        }
    }
}

// ------- Kernel D: out block + 3x3 broadcast store (2-row interleave) -------
extern "C" __global__ __launch_bounds__(256)
void k_outbc(const float* __restrict__ h1,
             const float* __restrict__ Wo, const float* __restrict__ bo_,
             const float* __restrict__ go, const float* __restrict__ beo,
             float* __restrict__ out) {
    int lane = threadIdx.x & 63;
    int wid = __builtin_amdgcn_readfirstlane(threadIdx.x >> 6);
    int wg = blockIdx.x * 4 + wid;
    float Wc[64];
#pragma unroll
    for (int k = 0; k < 64; ++k) Wc[k] = Wo[k * 64 + lane];
    float ob = bo_[lane], og = go[lane], obe = beo[lane];
    int row0 = wg * 16;
    for (int i = 0; i < 16; i += 2) {
        int rowA = row0 + i;
        int rowB = rowA + 1;
        const float* pA = h1 + (size_t)rowA * 64;   // wave-uniform -> s_load
        const float* pB = h1 + (size_t)rowB * 64;
        float a0 = ob, a1 = 0.f, a2 = 0.f, a3 = 0.f;
        float c0 = ob, c1 = 0.f, c2 = 0.f, c3 = 0.f;
#pragma unroll
        for (int k = 0; k < 64; k += 4) {
            a0 = fmaf(pA[k + 0], Wc[k + 0], a0);
            c0 = fmaf(pB[k + 0], Wc[k + 0], c0);
            a1 = fmaf(pA[k + 1], Wc[k + 1], a1);
            c1 = fmaf(pB[k + 1], Wc[k + 1], c1);
            a2 = fmaf(pA[k + 2], Wc[k + 2], a2);
            c2 = fmaf(pB[k + 2], Wc[k + 2], c2);
            a3 = fmaf(pA[k + 3], Wc[k + 3], a3);
            c3 = fmaf(pB[k + 3], Wc[k + 3], c3);
        }
        float yA = (a0 + a1) + (a2 + a3);
        float yB = (c0 + c1) + (c2 + c3);
        // interleaved variance butterflies: two independent DS chains overlap
        float sA = yA * yA, sB = yB * yB;
#pragma unroll
        for (int off = 32; off > 0; off >>= 1) {
            sA += __shfl_xor(sA, off, 64);
            sB += __shfl_xor(sB, off, 64);
        }
        float oA = gelu_exact(yA * rsqrtf(sA * (1.0f / 64.0f) + 1e-5f) * og + obe);
        float oB = gelu_exact(yB * rsqrtf(sB * (1.0f / 64.0f) + 1e-5f) * og + obe);
        // broadcast each to its 3x3 pixel patch
#pragma unroll
        for (int t = 0; t < 2; ++t) {
            int row = t == 0 ? rowA : rowB;
            float o = t == 0 ? oA : oB;
            int b = row >> 12;
            int rem = row & 4095;
            int wy = rem >> 7, wx = (rem >> 2) & 31, q = rem & 3;
            int y0p = wy * 6 + (q >> 1) * 3;
            int x0p = wx * 6 + (q & 1) * 3;
            float* obase = out + (((size_t)b * HH + y0p) * WW + x0p) * CC + lane;
#pragma unroll
            for (int dy = 0; dy < 3; ++dy) {
#pragma unroll
                for (int dx = 0; dx < 3; ++dx) {
                    obase[((size_t)dy * WW + dx) * CC] = o;
                }
            }
        }
    }
}

extern "C" void kernel_launch(void* const* d_in, const int* in_sizes, int n_in,
                              void* d_out, int out_size, void* d_ws, size_t ws_size,
                              hipStream_t stream) {
    const float* h   = (const float*)d_in[0];
    const float* tW  = (const float*)d_in[1];
    const float* tb  = (const float*)d_in[2];
    const float* tg  = (const float*)d_in[3];
    const float* tbe = (const float*)d_in[4];
    const float* fW  = (const float*)d_in[5];
    const float* fb  = (const float*)d_in[6];
    const float* fg  = (const float*)d_in[7];
    const float* fbe = (const float*)d_in[8];
    const float* oW  = (const float*)d_in[9];
    const float* ob  = (const float*)d_in[10];
    const float* og  = (const float*)d_in[11];
    const float* obe = (const float*)d_in[12];
    float* out = (float*)d_out;

    char* ws = (char*)d_ws;
    float* S   = (float*)(ws);               // 33,554,432 B; reused as h1
    float* tok = (float*)(ws + 33554432);    // 16,777,216 B
    float* h1  = S;
    float* cw  = (float*)(ws + 67108864);    // centered weights/biases
    float* Wtc = cw,          *Wfc = cw + 4096, *Woc = cw + 8192;
    float* btc = cw + 12288,  *bfc = cw + 12352, *boc = cw + 12416;

    hipLaunchKernelGGL(k_blocksum, dim3(2049), dim3(256), 0, stream,
                       h, S, tW, tb, fW, fb, oW, ob, cw);
    hipLaunchKernelGGL(k_token, dim3(1024), dim3(256), 0, stream,
                       S, Wtc, btc, tg, tbe, tok);
    hipLaunchKernelGGL(k_fuse, dim3(2048), dim3(256), 0, stream,
                       tok, Wfc, bfc, fg, fbe, h1);
    hipLaunchKernelGGL(k_outbc, dim3(2048), dim3(256), 0, stream,
                       h1, Woc, boc, og, obe, out);
}

// Round 4
// 619.141 us; speedup vs baseline: 1.0221x; 1.0221x over previous
//
#include <hip/hip_runtime.h>
#include <math.h>

// GraphSwinWindowContext: B=32, H=W=192, C=64, WS=6, SS=3, NH=NW=32. fp32 in/out.
//
// Output has only B*32*32*4 = 131072 distinct C-vectors (constant per
// (window, quadrant) 3x3 patch) -> per-pixel 64x64 linears collapse 9x.
//
// Round-7: consolidation. Evidence from r4(622)/r5(632)/r6(633): C/D time is
// invariant under readlane-VALU vs s_load matvec forms -> they are latency/
// memory-floor bound, and the s_load forms cost ~10us (scalar-cache round
// trips). This round:
//  * C/D back to the proven-fastest per-lane-load + readlane matvec (r4 form),
//    keeping window-sharing in C (shared t0 partial, 320 vs 512 fma/window).
//  * C batch-issues all 5 row loads (t0 + 4x t1) before any matvec -> load
//    latency overlaps the shared matvec.
//  * B software-pipelined: #pragma unroll 2 on the row loop -> next row's 4
//    S-gathers issue during current row's matvec.
//  * D: 2-row interleave (two independent fmac/butterfly/gelu chains).
//  * Kept from r5/r6: centered weights (mean(y)==0 -> single variance
//    butterfly), prep folded into k_blocksum block 2048.
//
// Floor model (if this round ties ~622 again -> roofline): fills ~235us
// (harness, measured) + A ~75 (302MB read) + B ~35 + C ~35 + D ~75 (302MB
// write) + gaps ~25 = ~620us.
//
// Pipeline:
//  A) k_blocksum: 3x3-pixel block sums + weight centering    (reads 302MB)
//  B) k_token:    pooled(reg/shift) -> lin+LN+GELU -> tok    (65536 rows)
//  C) k_fuse:     tokreg+tokshift -> lin+LN+GELU -> h1       (131072 rows)
//  D) k_outbc:    h1 -> lin+LN+GELU -> broadcast 3x3 to out  (writes 302MB)
//
// ws layout:
//  [0, 33554432)        : S fp32 [B][64][64][C]   -- reused as h1 after k_token
//  [33554432, 50331648) : tok fp32 [2][B][32][32][C]
//  [67108864, +49.4KB)  : centered Wt',Wf',Wo' (4096 fl each) + bt',bf',bo'

#define HH 192
#define WW 192
#define CC 64

__device__ __forceinline__ float gelu_exact(float x) {
    return 0.5f * x * (1.0f + erff(x * 0.70710678118654752440f));
}
__device__ __forceinline__ float wsum64(float v) {
#pragma unroll
    for (int off = 32; off > 0; off >>= 1) v += __shfl_xor(v, off, 64);
    return v;
}
// Broadcast lane k's value to all lanes: v_readlane_b32 (VALU, no DS).
__device__ __forceinline__ float bcast(float v, int k) {
    return __int_as_float(__builtin_amdgcn_readlane(__float_as_int(v), k));
}
// LN with pre-centered weights: mean(y)==0, only variance needs a reduction.
__device__ __forceinline__ float ln_gelu_c(float y, float g, float b) {
    float s2 = y * y;
#pragma unroll
    for (int off = 32; off > 0; off >>= 1) s2 += __shfl_xor(s2, off, 64);
    float v = s2 * (1.0f / 64.0f);
    return gelu_exact(y * rsqrtf(v + 1e-5f) * g + b);
}
// y_i += broadcast-matvec partials: 64 readlane+fma on 4 accumulators.
__device__ __forceinline__ void mac64_rl(float v, const float* Wc,
                                         float& y0, float& y1, float& y2, float& y3) {
#pragma unroll
    for (int k = 0; k < 64; k += 4) {
        y0 = fmaf(bcast(v, k + 0), Wc[k + 0], y0);
        y1 = fmaf(bcast(v, k + 1), Wc[k + 1], y1);
        y2 = fmaf(bcast(v, k + 2), Wc[k + 2], y2);
        y3 = fmaf(bcast(v, k + 3), Wc[k + 3], y3);
    }
}

// ------- Kernel A: 3x3 pixel-block channel sums + weight centering ----------
// blocks 0..2047: S[b][by][bx][c] = sum_{3x3} grid. block 2048: center W,b.
extern "C" __global__ __launch_bounds__(256)
void k_blocksum(const float* __restrict__ h, float* __restrict__ S,
                const float* __restrict__ W0, const float* __restrict__ b0,
                const float* __restrict__ W1, const float* __restrict__ b1,
                const float* __restrict__ W2, const float* __restrict__ b2,
                float* __restrict__ cw) {
    if (blockIdx.x == 2048) {                 // ---- prep path (3 waves) ----
        if (threadIdx.x >= 192) return;
        int lane = threadIdx.x & 63;
        int w = threadIdx.x >> 6;             // 0..2
        const float* W  = (w == 0) ? W0 : (w == 1) ? W1 : W2;
        const float* bs = (w == 0) ? b0 : (w == 1) ? b1 : b2;
        float* Wo = cw + w * 4096;
        float* bo = cw + 12288 + w * 64;
        for (int k = 0; k < 64; ++k) {
            float v = W[k * 64 + lane];
            Wo[k * 64 + lane] = v - wsum64(v) * (1.0f / 64.0f);
        }
        float bv = bs[lane];
        bo[lane] = bv - wsum64(bv) * (1.0f / 64.0f);
        return;
    }
    int bby = blockIdx.x;                     // b*64 + by
    int b = bby >> 6, by = bby & 63;
    for (int item = threadIdx.x; item < 512; item += 256) {
        int bx = item >> 3;
        int c0 = (item & 7) * 8;
        float acc[8] = {0.f, 0.f, 0.f, 0.f, 0.f, 0.f, 0.f, 0.f};
#pragma unroll
        for (int dy = 0; dy < 3; ++dy) {
#pragma unroll
            for (int dx = 0; dx < 3; ++dx) {
                int y = by * 3 + dy, x = bx * 3 + dx;
                const float4* p = reinterpret_cast<const float4*>(
                    h + (((size_t)b * HH + y) * WW + x) * CC + c0);
                float4 v0 = p[0], v1 = p[1];
                acc[0] += v0.x; acc[1] += v0.y; acc[2] += v0.z; acc[3] += v0.w;
                acc[4] += v1.x; acc[5] += v1.y; acc[6] += v1.z; acc[7] += v1.w;
            }
        }
        float4* o = reinterpret_cast<float4*>(S + (((size_t)bby) * 64 + bx) * CC + c0);
        o[0] = make_float4(acc[0], acc[1], acc[2], acc[3]);
        o[1] = make_float4(acc[4], acc[5], acc[6], acc[7]);
    }
}

// ---------------- Kernel B: token projection (reg + shifted) ----------------
// rows: mode(2) x b(32) x wy(32) x wx(32) = 65536; one wave computes 16 rows.
// unroll 2: next row's 4 S-gathers issue under current row's matvec.
extern "C" __global__ __launch_bounds__(256)
void k_token(const float* __restrict__ S,
             const float* __restrict__ Wt, const float* __restrict__ bt,
             const float* __restrict__ gt, const float* __restrict__ bet,
             float* __restrict__ tok) {
    int lane = threadIdx.x & 63;
    int wg = blockIdx.x * 4 + (threadIdx.x >> 6);
    float Wc[64];
#pragma unroll
    for (int k = 0; k < 64; ++k) Wc[k] = Wt[k * 64 + lane];
    float bias = bt[lane], gg = gt[lane], bb = bet[lane];
    int row0 = wg * 16;
#pragma unroll 2
    for (int i = 0; i < 16; ++i) {
        int row = row0 + i;
        int mode = row >> 15;                 // wave-uniform (16 | 32768)
        int r = row & 32767;
        int b = r >> 10, wy = (r >> 5) & 31, wx = r & 31;
        int r0, r1, c0, c1;
        if (mode == 0) { r0 = 2 * wy;     r1 = 2 * wy + 1;        c0 = 2 * wx;     c1 = 2 * wx + 1; }
        else           { r0 = 2 * wy + 1; r1 = (2 * wy + 2) & 63; c0 = 2 * wx + 1; c1 = (2 * wx + 2) & 63; }
        const float* Sb = S + (size_t)b * 64 * 64 * 64;
        float pooled = (Sb[(r0 * 64 + c0) * 64 + lane] + Sb[(r0 * 64 + c1) * 64 + lane] +
                        Sb[(r1 * 64 + c0) * 64 + lane] + Sb[(r1 * 64 + c1) * 64 + lane]) * (1.0f / 36.0f);
        float y0 = bias, y1 = 0.f, y2 = 0.f, y3 = 0.f;
        mac64_rl(pooled, Wc, y0, y1, y2, y3);
        float y = (y0 + y1) + (y2 + y3);
        tok[(size_t)row * 64 + lane] = ln_gelu_c(y, gg, bb);
    }
}

// ------- Kernel C: fuse block (per-lane loads + readlane, window-shared) ----
// rows: b(5)|wy(5)|wx(5)|q(2) = 131072; one wave = 4 windows x 4 quadrants.
// All 5 row-loads of a window issue before any matvec (latency overlap).
extern "C" __global__ __launch_bounds__(256)
void k_fuse(const float* __restrict__ tok,
            const float* __restrict__ Wf, const float* __restrict__ bf_,
            const float* __restrict__ gf, const float* __restrict__ bef,
            float* __restrict__ h1) {
    int lane = threadIdx.x & 63;
    int wid = __builtin_amdgcn_readfirstlane(threadIdx.x >> 6);
    int wg = blockIdx.x * 4 + wid;
    float Wc[64];
#pragma unroll
    for (int k = 0; k < 64; ++k) Wc[k] = Wf[k * 64 + lane];
    float fb = bf_[lane], fg = gf[lane], fbe = bef[lane];
    int row0 = wg * 16;                       // q bits 0 -> wx0 % 4 == 0
    int b = row0 >> 12;
    int rem = row0 & 4095;
    int wy = rem >> 7, wx0 = (rem >> 2) & 31;
    const float* t0 = tok + (size_t)b * 65536;
    const float* t1 = tok + 2097152 + (size_t)b * 65536;
    for (int j = 0; j < 4; ++j) {
        int wx = wx0 + j;                     // <= 31, no wrap
        // issue all 5 loads up front
        float t0v = t0[(wy * 32 + wx) * 64 + lane];
        float t1v[4];
#pragma unroll
        for (int q = 0; q < 4; ++q) {
            int sy = (wy + 31 + (q >> 1)) & 31;
            int sx = (wx + 31 + (q & 1)) & 31;
            t1v[q] = t1[(sy * 32 + sx) * 64 + lane];
        }
        // shared term: bias + t0[wy][wx] @ W (once for 4 quadrants)
        float s0 = fb, s1 = 0.f, s2 = 0.f, s3 = 0.f;
        mac64_rl(t0v, Wc, s0, s1, s2, s3);
#pragma unroll
        for (int q = 0; q < 4; ++q) {
            float y0 = s0, y1 = s1, y2 = s2, y3 = s3;
            mac64_rl(t1v[q], Wc, y0, y1, y2, y3);
            float y = (y0 + y1) + (y2 + y3);
            h1[(size_t)(row0 + j * 4 + q) * 64 + lane] = ln_gelu_c(y, fg, fbe);
        }
    }
}

// ------- Kernel D: out block + 3x3 broadcast store (2-row interleave) -------
extern "C" __global__ __launch_bounds__(256)
void k_outbc(const float* __restrict__ h1,
             const float* __restrict__ Wo, const float* __restrict__ bo_,
             const float* __restrict__ go, const float* __restrict__ beo,
             float* __restrict__ out) {
    int lane = threadIdx.x & 63;
    int wid = __builtin_amdgcn_readfirstlane(threadIdx.x >> 6);
    int wg = blockIdx.x * 4 + wid;
    float Wc[64];
#pragma unroll
    for (int k = 0; k < 64; ++k) Wc[k] = Wo[k * 64 + lane];
    float ob = bo_[lane], og = go[lane], obe = beo[lane];
    int row0 = wg * 16;
    for (int i = 0; i < 16; i += 2) {
        int rowA = row0 + i;
        int rowB = rowA + 1;
        float hA = h1[(size_t)rowA * 64 + lane];
        float hB = h1[(size_t)rowB * 64 + lane];
        float a0 = ob, a1 = 0.f, a2 = 0.f, a3 = 0.f;
        float c0 = ob, c1 = 0.f, c2 = 0.f, c3 = 0.f;
#pragma unroll
        for (int k = 0; k < 64; k += 4) {
            a0 = fmaf(bcast(hA, k + 0), Wc[k + 0], a0);
            c0 = fmaf(bcast(hB, k + 0), Wc[k + 0], c0);
            a1 = fmaf(bcast(hA, k + 1), Wc[k + 1], a1);
            c1 = fmaf(bcast(hB, k + 1), Wc[k + 1], c1);
            a2 = fmaf(bcast(hA, k + 2), Wc[k + 2], a2);
            c2 = fmaf(bcast(hB, k + 2), Wc[k + 2], c2);
            a3 = fmaf(bcast(hA, k + 3), Wc[k + 3], a3);
            c3 = fmaf(bcast(hB, k + 3), Wc[k + 3], c3);
        }
        float yA = (a0 + a1) + (a2 + a3);
        float yB = (c0 + c1) + (c2 + c3);
        // interleaved variance butterflies: two independent DS chains overlap
        float sA = yA * yA, sB = yB * yB;
#pragma unroll
        for (int off = 32; off > 0; off >>= 1) {
            sA += __shfl_xor(sA, off, 64);
            sB += __shfl_xor(sB, off, 64);
        }
        float oA = gelu_exact(yA * rsqrtf(sA * (1.0f / 64.0f) + 1e-5f) * og + obe);
        float oB = gelu_exact(yB * rsqrtf(sB * (1.0f / 64.0f) + 1e-5f) * og + obe);
#pragma unroll
        for (int t = 0; t < 2; ++t) {
            int row = t == 0 ? rowA : rowB;
            float o = t == 0 ? oA : oB;
            int b = row >> 12;
            int rem = row & 4095;
            int wy = rem >> 7, wx = (rem >> 2) & 31, q = rem & 3;
            int y0p = wy * 6 + (q >> 1) * 3;
            int x0p = wx * 6 + (q & 1) * 3;
            float* obase = out + (((size_t)b * HH + y0p) * WW + x0p) * CC + lane;
#pragma unroll
            for (int dy = 0; dy < 3; ++dy) {
#pragma unroll
                for (int dx = 0; dx < 3; ++dx) {
                    obase[((size_t)dy * WW + dx) * CC] = o;
                }
            }
        }
    }
}

extern "C" void kernel_launch(void* const* d_in, const int* in_sizes, int n_in,
                              void* d_out, int out_size, void* d_ws, size_t ws_size,
                              hipStream_t stream) {
    const float* h   = (const float*)d_in[0];
    const float* tW  = (const float*)d_in[1];
    const float* tb  = (const float*)d_in[2];
    const float* tg  = (const float*)d_in[3];
    const float* tbe = (const float*)d_in[4];
    const float* fW  = (const float*)d_in[5];
    const float* fb  = (const float*)d_in[6];
    const float* fg  = (const float*)d_in[7];
    const float* fbe = (const float*)d_in[8];
    const float* oW  = (const float*)d_in[9];
    const float* ob  = (const float*)d_in[10];
    const float* og  = (const float*)d_in[11];
    const float* obe = (const float*)d_in[12];
    float* out = (float*)d_out;

    char* ws = (char*)d_ws;
    float* S   = (float*)(ws);               // 33,554,432 B; reused as h1
    float* tok = (float*)(ws + 33554432);    // 16,777,216 B
    float* h1  = S;
    float* cw  = (float*)(ws + 67108864);    // centered weights/biases
    float* Wtc = cw,          *Wfc = cw + 4096, *Woc = cw + 8192;
    float* btc = cw + 12288,  *bfc = cw + 12352, *boc = cw + 12416;

    hipLaunchKernelGGL(k_blocksum, dim3(2049), dim3(256), 0, stream,
                       h, S, tW, tb, fW, fb, oW, ob, cw);
    hipLaunchKernelGGL(k_token, dim3(1024), dim3(256), 0, stream,
                       S, Wtc, btc, tg, tbe, tok);
    hipLaunchKernelGGL(k_fuse, dim3(2048), dim3(256), 0, stream,
                       tok, Wfc, bfc, fg, fbe, h1);
    hipLaunchKernelGGL(k_outbc, dim3(2048), dim3(256), 0, stream,
                       h1, Woc, boc, og, obe, out);
}